// Round 1
// baseline (172.390 us; speedup 1.0000x reference)
//
#include <hip/hip_runtime.h>
#include <stdint.h>

#define NB 2048      // groups
#define D 128
#define NPG 91
#define ROWS 96

typedef __attribute__((ext_vector_type(8))) short short8;
typedef __attribute__((ext_vector_type(4))) float f32x4;

__device__ __forceinline__ unsigned bf16pk(float a, float b) {
  unsigned ua = __float_as_uint(a);
  unsigned ub = __float_as_uint(b);
  ua += 0x7fffu + ((ua >> 16) & 1u);   // RNE
  ub += 0x7fffu + ((ub >> 16) & 1u);
  return (ua >> 16) | (ub & 0xffff0000u);
}

__device__ __forceinline__ float sigf(float x) {
  return 1.0f / (1.0f + __expf(-x));
}

// K0: fv[o][b][h] = sum_d feats[last_idx[o][b]][d] * Wv[o][d][h]
__global__ void fv_kernel(const float* __restrict__ feats,
                          const float* __restrict__ Wv,
                          const int* __restrict__ last_idx,
                          float* __restrict__ fv) {
  __shared__ float rows[16][128];
  __shared__ int lidx[16];
  const int o = blockIdx.y;
  const int b0 = blockIdx.x * 16;
  const int t = threadIdx.x;
  if (t < 16) lidx[t] = last_idx[o * NB + b0 + t];
  __syncthreads();
  #pragma unroll
  for (int i = 0; i < 8; ++i) {
    int el = t + i * 256;
    int r = el >> 7, d = el & 127;
    rows[r][d] = feats[(size_t)lidx[r] * D + d];
  }
  __syncthreads();
  const int h = t & 127, half = t >> 7;
  float acc[8];
  #pragma unroll
  for (int j = 0; j < 8; ++j) acc[j] = 0.f;
  const float* wvo = Wv + (size_t)o * D * D + h;
  for (int d0 = 0; d0 < D; d0 += 4) {
    float w0 = wvo[(d0 + 0) * D], w1 = wvo[(d0 + 1) * D];
    float w2 = wvo[(d0 + 2) * D], w3 = wvo[(d0 + 3) * D];
    #pragma unroll
    for (int j = 0; j < 8; ++j) {
      const float4 f = *(const float4*)&rows[half * 8 + j][d0];
      acc[j] += f.x * w0 + f.y * w1 + f.z * w2 + f.w * w3;
    }
  }
  #pragma unroll
  for (int j = 0; j < 8; ++j)
    fv[((size_t)o * NB + b0 + half * 8 + j) * D + h] = acc[j];
}

// K1: one block per group. bf16 MFMA for feat_u, fused sigmoid/We reduce,
// per-order softmax over 91 nodes, fp32 weighted sum of feats.
__global__ __launch_bounds__(256) void sihg_main(
    const float* __restrict__ feats,
    const float* __restrict__ Wu,
    const float* __restrict__ bu,
    const float* __restrict__ We,
    const float* __restrict__ fv,
    float* __restrict__ out) {
  __shared__ __align__(16) char lds[64128];
  constexpr int A_OFF  = 0;       // bf16 [96][128] swizzled rows (256B each)
  constexpr int W_OFF  = 24576;   // bf16 WuT [h=128][k=128] swizzled
  constexpr int EP_OFF = 57344;   // float [4][3][96] e-partials / reuse for part[2][3][128]
  constexpr int BFV_OFF = 61952;  // float[128]
  constexpr int WEL_OFF = 62464;  // float[128]
  constexpr int AL_OFF = 62976;   // float [3][96]

  const int t = threadIdx.x;
  const int b = blockIdx.x;
  const int w = t >> 6;     // wave 0..3
  const int l = t & 63;
  const int g = l >> 4;
  const int lm = l & 15;

  float (*ep)[3][96] = (float (*)[3][96])(lds + EP_OFF);
  float* bfv = (float*)(lds + BFV_OFF);
  float* wel = (float*)(lds + WEL_OFF);
  float (*alpha)[96] = (float (*)[96])(lds + AL_OFF);

  const float* fbase = feats + (size_t)b * NPG * D;

  // ---- phase 1: feats -> LDS bf16, swizzled; rows 91..95 zero-padded
  #pragma unroll
  for (int i = 0; i < 6; ++i) {
    int c = t + i * 256;              // 1536 chunks of 8 bf16
    int r = c >> 4, d0 = (c & 15) * 8;
    uint4 pk4;
    if (r < NPG) {
      const float* src = fbase + r * D + d0;
      float4 f0 = *(const float4*)(src);
      float4 f1 = *(const float4*)(src + 4);
      pk4.x = bf16pk(f0.x, f0.y);
      pk4.y = bf16pk(f0.z, f0.w);
      pk4.z = bf16pk(f1.x, f1.y);
      pk4.w = bf16pk(f1.z, f1.w);
    } else {
      pk4.x = 0u; pk4.y = 0u; pk4.z = 0u; pk4.w = 0u;
    }
    int off = r * 256 + ((d0 * 2) ^ ((r & 7) << 4));
    *(uint4*)(lds + A_OFF + off) = pk4;
  }

  const int h = t & 127, hf = t >> 7;

  for (int o = 0; o < 3; ++o) {
    __syncthreads();   // previous order's MFMA reads of WuT done
    // ---- stage Wu[o] transposed -> WuT[h][k] bf16, swizzled
    {
      const float* col = Wu + (size_t)o * D * D + h;
      #pragma unroll
      for (int c = 0; c < 8; ++c) {
        int d0 = (hf * 8 + c) * 8;
        uint4 pk4;
        pk4.x = bf16pk(col[(d0 + 0) * D], col[(d0 + 1) * D]);
        pk4.y = bf16pk(col[(d0 + 2) * D], col[(d0 + 3) * D]);
        pk4.z = bf16pk(col[(d0 + 4) * D], col[(d0 + 5) * D]);
        pk4.w = bf16pk(col[(d0 + 6) * D], col[(d0 + 7) * D]);
        int off = h * 256 + ((d0 * 2) ^ ((h & 7) << 4));
        *(uint4*)(lds + W_OFF + off) = pk4;
      }
    }
    if (t < 128) {
      bfv[t] = fv[((size_t)o * NB + b) * D + t] + bu[o * D + t];
      wel[t] = We[o * D + t];
    }
    __syncthreads();

    const float bfva = bfv[32 * w + lm],      bfvb = bfv[32 * w + 16 + lm];
    const float wea  = wel[32 * w + lm],      web  = wel[32 * w + 16 + lm];
    const char* b0b = lds + W_OFF + (32 * w + lm) * 256;
    const char* b1b = lds + W_OFF + (32 * w + 16 + lm) * 256;
    const int s0 = ((32 * w + lm) & 7) << 4;
    const int s1 = ((32 * w + 16 + lm) & 7) << 4;

    for (int mt = 0; mt < 6; ++mt) {
      const int arow = mt * 16 + lm;
      const char* ab = lds + A_OFF + arow * 256;
      const int sa = (arow & 7) << 4;
      f32x4 acc0 = {0.f, 0.f, 0.f, 0.f};
      f32x4 acc1 = {0.f, 0.f, 0.f, 0.f};
      #pragma unroll
      for (int kk = 0; kk < 4; ++kk) {
        const int cb = kk * 64 + g * 16;   // identical k-addressing for A and B
        short8 a  = *(const short8*)(ab  + (cb ^ sa));
        short8 b0 = *(const short8*)(b0b + (cb ^ s0));
        short8 b1 = *(const short8*)(b1b + (cb ^ s1));
        acc0 = __builtin_amdgcn_mfma_f32_16x16x32_bf16(a, b0, acc0, 0, 0, 0);
        acc1 = __builtin_amdgcn_mfma_f32_16x16x32_bf16(a, b1, acc1, 0, 0, 0);
      }
      // e contribution: sigmoid(acc + bu + fv) * We, reduced over this wave's 32 h
      #pragma unroll
      for (int r = 0; r < 4; ++r) {
        float v = sigf(acc0[r] + bfva) * wea + sigf(acc1[r] + bfvb) * web;
        v += __shfl_xor(v, 1);
        v += __shfl_xor(v, 2);
        v += __shfl_xor(v, 4);
        v += __shfl_xor(v, 8);
        if (lm == 0) ep[w][o][mt * 16 + g * 4 + r] = v;  // C/D: row=(l>>4)*4+r
      }
    }
  }
  __syncthreads();

  // ---- softmax per order (wave o handles order o, rows >= 91 masked)
  if (w < 3) {
    const int o = w;
    const int n1 = l, n2 = l + 64;
    float e1 = -1e30f, e2 = -1e30f;
    if (n1 < NPG) e1 = ep[0][o][n1] + ep[1][o][n1] + ep[2][o][n1] + ep[3][o][n1];
    if (n2 < NPG) e2 = ep[0][o][n2] + ep[1][o][n2] + ep[2][o][n2] + ep[3][o][n2];
    float mx = fmaxf(e1, e2);
    #pragma unroll
    for (int m = 1; m < 64; m <<= 1) mx = fmaxf(mx, __shfl_xor(mx, m));
    float x1 = (n1 < NPG) ? __expf(e1 - mx) : 0.f;
    float x2 = (n2 < NPG) ? __expf(e2 - mx) : 0.f;
    float s = x1 + x2;
    #pragma unroll
    for (int m = 1; m < 64; m <<= 1) s += __shfl_xor(s, m);
    float inv = 1.f / s;
    if (n1 < NPG) alpha[o][n1] = x1 * inv;
    if (n2 < NPG) alpha[o][n2] = x2 * inv;
  }
  __syncthreads();

  // ---- weighted sum: re-read feats fp32 (L2-warm), 3 orders per load
  float (*part)[3][128] = (float (*)[3][128])(lds + EP_OFF);
  {
    const int d = t & 127;
    float a0 = 0.f, a1 = 0.f, a2 = 0.f;
    for (int n = hf; n < NPG; n += 2) {
      float f = fbase[n * D + d];
      a0 += alpha[0][n] * f;
      a1 += alpha[1][n] * f;
      a2 += alpha[2][n] * f;
    }
    part[hf][0][d] = a0;
    part[hf][1][d] = a1;
    part[hf][2][d] = a2;
  }
  __syncthreads();
  for (int slot = t; slot < 384; slot += 256) {
    int o = slot >> 7, dd = slot & 127;
    out[((size_t)b * 3 + o) * D + dd] = part[0][o][dd] + part[1][o][dd];
  }
}

extern "C" void kernel_launch(void* const* d_in, const int* in_sizes, int n_in,
                              void* d_out, int out_size, void* d_ws, size_t ws_size,
                              hipStream_t stream) {
  const float* feats    = (const float*)d_in[0];
  const float* Wu       = (const float*)d_in[1];
  const float* bu       = (const float*)d_in[2];
  const float* Wv       = (const float*)d_in[3];
  const float* We       = (const float*)d_in[4];
  const int*   last_idx = (const int*)d_in[6];
  float* out = (float*)d_out;
  float* fvb = (float*)d_ws;   // 3*2048*128 fp32 = 3 MB

  dim3 g0(128, 3);
  fv_kernel<<<g0, 256, 0, stream>>>(feats, Wv, last_idx, fvb);
  sihg_main<<<NB, 256, 0, stream>>>(feats, Wu, bu, We, fvb, out);
}

// Round 2
// 94.416 us; speedup vs baseline: 1.8259x; 1.8259x over previous
//
#include <hip/hip_runtime.h>
#include <stdint.h>

#define NB 2048      // groups
#define D 128
#define NPG 91
#define ROWS 96

typedef __attribute__((ext_vector_type(8))) short short8;
typedef __attribute__((ext_vector_type(4))) float f32x4;

__device__ __forceinline__ unsigned bf16pk(float a, float b) {
  unsigned ua = __float_as_uint(a);
  unsigned ub = __float_as_uint(b);
  ua += 0x7fffu + ((ua >> 16) & 1u);   // RNE
  ub += 0x7fffu + ((ub >> 16) & 1u);
  return (ua >> 16) | (ub & 0xffff0000u);
}

__device__ __forceinline__ float sigf(float x) {
  return 1.0f / (1.0f + __expf(-x));
}

// K0a: fv[o][b][h] = sum_d feats[last_idx[o][b]][d] * Wv[o][d][h]  + bu[o][h]
__global__ void fv_kernel(const float* __restrict__ feats,
                          const float* __restrict__ Wv,
                          const float* __restrict__ bu,
                          const int* __restrict__ last_idx,
                          float* __restrict__ fv) {
  __shared__ float rows[16][128];
  __shared__ int lidx[16];
  const int o = blockIdx.y;
  const int b0 = blockIdx.x * 16;
  const int t = threadIdx.x;
  if (t < 16) lidx[t] = last_idx[o * NB + b0 + t];
  __syncthreads();
  #pragma unroll
  for (int i = 0; i < 8; ++i) {
    int el = t + i * 256;
    int r = el >> 7, d = el & 127;
    rows[r][d] = feats[(size_t)lidx[r] * D + d];
  }
  __syncthreads();
  const int h = t & 127, half = t >> 7;
  float acc[8];
  #pragma unroll
  for (int j = 0; j < 8; ++j) acc[j] = 0.f;
  const float* wvo = Wv + (size_t)o * D * D + h;
  for (int d0 = 0; d0 < D; d0 += 4) {
    float w0 = wvo[(d0 + 0) * D], w1 = wvo[(d0 + 1) * D];
    float w2 = wvo[(d0 + 2) * D], w3 = wvo[(d0 + 3) * D];
    #pragma unroll
    for (int j = 0; j < 8; ++j) {
      const float4 f = *(const float4*)&rows[half * 8 + j][d0];
      acc[j] += f.x * w0 + f.y * w1 + f.z * w2 + f.w * w3;
    }
  }
  const float bb = bu[o * D + h];
  #pragma unroll
  for (int j = 0; j < 8; ++j)
    fv[((size_t)o * NB + b0 + half * 8 + j) * D + h] = acc[j] + bb;
}

// K0b: pack Wu transposed to bf16 in MFMA B-fragment order:
// wupk[(o*4+kk)*512 + row*4 + g] (uint4) = Wu[o][kk*32+g*8 + 0..7][row] as 8 bf16
__global__ void wut_pack(const float* __restrict__ Wu, uint4* __restrict__ wupk) {
  const int o = blockIdx.x >> 2, kk = blockIdx.x & 3;
  const int t = threadIdx.x;
  #pragma unroll
  for (int i = 0; i < 2; ++i) {
    int idx = i * 256 + t;              // 0..511
    int row = idx >> 2, g = idx & 3;
    const float* src = Wu + (size_t)o * D * D + (kk * 32 + g * 8) * D + row;
    uint4 pk;
    pk.x = bf16pk(src[0 * D], src[1 * D]);
    pk.y = bf16pk(src[2 * D], src[3 * D]);
    pk.z = bf16pk(src[4 * D], src[5 * D]);
    pk.w = bf16pk(src[6 * D], src[7 * D]);
    wupk[(size_t)blockIdx.x * 512 + idx] = pk;
  }
}

// K1: one block per group. bf16 MFMA for feat_u (B-fragments from registers),
// fused sigmoid/We reduce, per-order softmax, fp32 weighted sum.
__global__ __launch_bounds__(256, 4) void sihg_main(
    const float* __restrict__ feats,
    const uint4* __restrict__ wupk,
    const float* __restrict__ We,
    const float* __restrict__ fvb,
    float* __restrict__ out) {
  __shared__ __align__(16) char lds[38016];
  constexpr int A_OFF  = 0;       // bf16 [96][128] swizzled rows (256B each)
  constexpr int EP_OFF = 24576;   // float [4][3][96] e-partials / reuse part[8][384]
  constexpr int AL_OFF = 36864;   // float [3][96]

  const int t = threadIdx.x;
  const int b = blockIdx.x;
  const int w = t >> 6;     // wave 0..3
  const int l = t & 63;
  const int g = l >> 4;
  const int lm = l & 15;

  float (*ep)[3][96] = (float (*)[3][96])(lds + EP_OFF);
  float (*alpha)[96] = (float (*)[96])(lds + AL_OFF);

  const float* fbase = feats + (size_t)b * NPG * D;

  // ---- phase 1: feats -> LDS bf16, swizzled; rows 91..95 zero-padded
  #pragma unroll
  for (int i = 0; i < 6; ++i) {
    int c = t + i * 256;              // 1536 chunks of 8 bf16
    int r = c >> 4, d0 = (c & 15) * 8;
    uint4 pk4;
    if (r < NPG) {
      const float* src = fbase + r * D + d0;
      float4 f0 = *(const float4*)(src);
      float4 f1 = *(const float4*)(src + 4);
      pk4.x = bf16pk(f0.x, f0.y);
      pk4.y = bf16pk(f0.z, f0.w);
      pk4.z = bf16pk(f1.x, f1.y);
      pk4.w = bf16pk(f1.z, f1.w);
    } else {
      pk4.x = 0u; pk4.y = 0u; pk4.z = 0u; pk4.w = 0u;
    }
    int off = r * 256 + ((d0 * 2) ^ ((r & 7) << 4));
    *(uint4*)(lds + A_OFF + off) = pk4;
  }
  __syncthreads();

  for (int o = 0; o < 3; ++o) {
    // ---- B fragments straight from pre-packed global (L2-hot, coalesced)
    short8 bf0[4], bf1[4];
    #pragma unroll
    for (int kk = 0; kk < 4; ++kk) {
      size_t base = (size_t)(o * 4 + kk) * 512;
      bf0[kk] = *(const short8*)&wupk[base + (32 * w + lm) * 4 + g];
      bf1[kk] = *(const short8*)&wupk[base + (32 * w + 16 + lm) * 4 + g];
    }
    const float bfva = fvb[((size_t)o * NB + b) * D + 32 * w + lm];
    const float bfvb = fvb[((size_t)o * NB + b) * D + 32 * w + 16 + lm];
    const float wea  = We[o * D + 32 * w + lm];
    const float web  = We[o * D + 32 * w + 16 + lm];

    for (int mt = 0; mt < 6; ++mt) {
      const int arow = mt * 16 + lm;
      const char* ab = lds + A_OFF + arow * 256;
      const int sa = (arow & 7) << 4;
      f32x4 acc0 = {0.f, 0.f, 0.f, 0.f};
      f32x4 acc1 = {0.f, 0.f, 0.f, 0.f};
      #pragma unroll
      for (int kk = 0; kk < 4; ++kk) {
        const int cb = kk * 64 + g * 16;   // same k-order as wupk layout
        short8 a = *(const short8*)(ab + (cb ^ sa));
        acc0 = __builtin_amdgcn_mfma_f32_16x16x32_bf16(a, bf0[kk], acc0, 0, 0, 0);
        acc1 = __builtin_amdgcn_mfma_f32_16x16x32_bf16(a, bf1[kk], acc1, 0, 0, 0);
      }
      #pragma unroll
      for (int r = 0; r < 4; ++r) {
        float v = sigf(acc0[r] + bfva) * wea + sigf(acc1[r] + bfvb) * web;
        v += __shfl_xor(v, 1);
        v += __shfl_xor(v, 2);
        v += __shfl_xor(v, 4);
        v += __shfl_xor(v, 8);
        if (lm == 0) ep[w][o][mt * 16 + g * 4 + r] = v;  // C/D: row=(l>>4)*4+r
      }
    }
  }
  __syncthreads();

  // ---- softmax per order (wave o handles order o, rows >= 91 masked)
  if (w < 3) {
    const int o = w;
    const int n1 = l, n2 = l + 64;
    float e1 = -1e30f, e2 = -1e30f;
    if (n1 < NPG) e1 = ep[0][o][n1] + ep[1][o][n1] + ep[2][o][n1] + ep[3][o][n1];
    if (n2 < NPG) e2 = ep[0][o][n2] + ep[1][o][n2] + ep[2][o][n2] + ep[3][o][n2];
    float mx = fmaxf(e1, e2);
    #pragma unroll
    for (int m = 1; m < 64; m <<= 1) mx = fmaxf(mx, __shfl_xor(mx, m));
    float x1 = (n1 < NPG) ? __expf(e1 - mx) : 0.f;
    float x2 = (n2 < NPG) ? __expf(e2 - mx) : 0.f;
    float s = x1 + x2;
    #pragma unroll
    for (int m = 1; m < 64; m <<= 1) s += __shfl_xor(s, m);
    float inv = 1.f / s;
    if (n1 < NPG) alpha[o][n1] = x1 * inv;
    if (n2 < NPG) alpha[o][n2] = x2 * inv;
  }
  __syncthreads();

  // ---- weighted sum: float4 loads, 8-way node-parallel
  {
    const int n_off = t >> 5;
    const int d4 = (t & 31) * 4;
    float a0x = 0.f, a0y = 0.f, a0z = 0.f, a0w = 0.f;
    float a1x = 0.f, a1y = 0.f, a1z = 0.f, a1w = 0.f;
    float a2x = 0.f, a2y = 0.f, a2z = 0.f, a2w = 0.f;
    for (int n = n_off; n < NPG; n += 8) {
      float4 f = *(const float4*)(fbase + n * D + d4);
      float al0 = alpha[0][n], al1 = alpha[1][n], al2 = alpha[2][n];
      a0x += f.x * al0; a0y += f.y * al0; a0z += f.z * al0; a0w += f.w * al0;
      a1x += f.x * al1; a1y += f.y * al1; a1z += f.z * al1; a1w += f.w * al1;
      a2x += f.x * al2; a2y += f.y * al2; a2z += f.z * al2; a2w += f.w * al2;
    }
    float* part = (float*)(lds + EP_OFF);   // [8][384]
    float4 s0 = {a0x, a0y, a0z, a0w};
    float4 s1 = {a1x, a1y, a1z, a1w};
    float4 s2 = {a2x, a2y, a2z, a2w};
    *(float4*)&part[n_off * 384 + 0 * 128 + d4] = s0;
    *(float4*)&part[n_off * 384 + 1 * 128 + d4] = s1;
    *(float4*)&part[n_off * 384 + 2 * 128 + d4] = s2;
  }
  __syncthreads();
  {
    const float* part = (const float*)(lds + EP_OFF);
    for (int slot = t; slot < 384; slot += 256) {
      float s = 0.f;
      #pragma unroll
      for (int j = 0; j < 8; ++j) s += part[j * 384 + slot];
      out[(size_t)b * 384 + slot] = s;
    }
  }
}

extern "C" void kernel_launch(void* const* d_in, const int* in_sizes, int n_in,
                              void* d_out, int out_size, void* d_ws, size_t ws_size,
                              hipStream_t stream) {
  const float* feats    = (const float*)d_in[0];
  const float* Wu       = (const float*)d_in[1];
  const float* bu       = (const float*)d_in[2];
  const float* Wv       = (const float*)d_in[3];
  const float* We       = (const float*)d_in[4];
  const int*   last_idx = (const int*)d_in[6];
  float* out = (float*)d_out;
  float* fvb  = (float*)d_ws;                              // 3*2048*128 f32 = 3 MB
  uint4* wupk = (uint4*)((char*)d_ws + 3 * NB * D * 4);    // 96 KB

  dim3 g0(128, 3);
  fv_kernel<<<g0, 256, 0, stream>>>(feats, Wv, bu, last_idx, fvb);
  wut_pack<<<12, 256, 0, stream>>>(Wu, wupk);
  sihg_main<<<NB, 256, 0, stream>>>(feats, wupk, We, fvb, out);
}

// Round 3
// 84.179 us; speedup vs baseline: 2.0479x; 1.1216x over previous
//
#include <hip/hip_runtime.h>
#include <hip/hip_bf16.h>
#include <stdint.h>

#define NB 2048      // groups
#define D 128
#define NPG 91
#define ROWS 96

typedef __attribute__((ext_vector_type(8))) short short8;
typedef __attribute__((ext_vector_type(4))) float f32x4;

__device__ __forceinline__ unsigned bf16pk(float a, float b) {
  __hip_bfloat162 h2 = __float22bfloat162_rn(make_float2(a, b));
  return *reinterpret_cast<unsigned*>(&h2);   // v_cvt_pk_bf16_f32
}

__device__ __forceinline__ float sigf(float x) {
  float e = __expf(-x);
  return __builtin_amdgcn_rcpf(1.0f + e);     // v_rcp_f32, ~1ulp
}

// K0a: fv[o][b][h] = sum_d feats[last_idx[o][b]][d] * Wv[o][d][h]  + bu[o][h]
__global__ void fv_kernel(const float* __restrict__ feats,
                          const float* __restrict__ Wv,
                          const float* __restrict__ bu,
                          const int* __restrict__ last_idx,
                          float* __restrict__ fv) {
  __shared__ float rows[16][128];
  __shared__ int lidx[16];
  const int o = blockIdx.y;
  const int b0 = blockIdx.x * 16;
  const int t = threadIdx.x;
  if (t < 16) lidx[t] = last_idx[o * NB + b0 + t];
  __syncthreads();
  #pragma unroll
  for (int i = 0; i < 8; ++i) {
    int el = t + i * 256;
    int r = el >> 7, d = el & 127;
    rows[r][d] = feats[(size_t)lidx[r] * D + d];
  }
  __syncthreads();
  const int h = t & 127, half = t >> 7;
  float acc[8];
  #pragma unroll
  for (int j = 0; j < 8; ++j) acc[j] = 0.f;
  const float* wvo = Wv + (size_t)o * D * D + h;
  for (int d0 = 0; d0 < D; d0 += 4) {
    float w0 = wvo[(d0 + 0) * D], w1 = wvo[(d0 + 1) * D];
    float w2 = wvo[(d0 + 2) * D], w3 = wvo[(d0 + 3) * D];
    #pragma unroll
    for (int j = 0; j < 8; ++j) {
      const float4 f = *(const float4*)&rows[half * 8 + j][d0];
      acc[j] += f.x * w0 + f.y * w1 + f.z * w2 + f.w * w3;
    }
  }
  const float bb = bu[o * D + h];
  #pragma unroll
  for (int j = 0; j < 8; ++j)
    fv[((size_t)o * NB + b0 + half * 8 + j) * D + h] = acc[j] + bb;
}

// K0b: pack Wu transposed to bf16 in MFMA B-fragment order:
// wupk[(o*4+kk)*512 + row*4 + g] (uint4) = Wu[o][kk*32+g*8 + 0..7][row] as 8 bf16
__global__ void wut_pack(const float* __restrict__ Wu, uint4* __restrict__ wupk) {
  const int o = blockIdx.x >> 2, kk = blockIdx.x & 3;
  const int t = threadIdx.x;
  #pragma unroll
  for (int i = 0; i < 2; ++i) {
    int idx = i * 256 + t;              // 0..511
    int row = idx >> 2, g = idx & 3;
    const float* src = Wu + (size_t)o * D * D + (kk * 32 + g * 8) * D + row;
    uint4 pk;
    pk.x = bf16pk(src[0 * D], src[1 * D]);
    pk.y = bf16pk(src[2 * D], src[3 * D]);
    pk.z = bf16pk(src[4 * D], src[5 * D]);
    pk.w = bf16pk(src[6 * D], src[7 * D]);
    wupk[(size_t)blockIdx.x * 512 + idx] = pk;
  }
}

// K1: one block per group, 5 blocks/CU. bf16 MFMA for feat_u (B in registers),
// fused sigmoid/We reduce, per-order softmax, fp32 weighted sum.
__global__ __launch_bounds__(256, 5) void sihg_main(
    const float* __restrict__ feats,
    const uint4* __restrict__ wupk,
    const float* __restrict__ We,
    const float* __restrict__ fvb,
    float* __restrict__ out) {
  __shared__ __align__(16) char lds[30336];
  constexpr int A_OFF  = 0;       // bf16 [96][128] swizzled (256B rows); later part[8][384] f32
  constexpr int EP_OFF = 24576;   // float [4][3][96] e-partials
  constexpr int AL_OFF = 29184;   // float [3][96]

  const int t = threadIdx.x;
  const int b = blockIdx.x;
  const int w = t >> 6;     // wave 0..3
  const int l = t & 63;
  const int g = l >> 4;
  const int lm = l & 15;

  float (*ep)[3][96] = (float (*)[3][96])(lds + EP_OFF);
  float (*alpha)[96] = (float (*)[96])(lds + AL_OFF);

  const float* fbase = feats + (size_t)b * NPG * D;
  const int h1 = 32 * w + lm, h2 = 32 * w + 16 + lm;

  // ---- hoisted scalar loads (complete under the staging barrier's drain)
  float bfva_a[3], bfvb_a[3], wea_a[3], web_a[3];
  #pragma unroll
  for (int o = 0; o < 3; ++o) {
    bfva_a[o] = fvb[((size_t)o * NB + b) * D + h1];
    bfvb_a[o] = fvb[((size_t)o * NB + b) * D + h2];
    wea_a[o]  = We[o * D + h1];
    web_a[o]  = We[o * D + h2];
  }
  // o=0 B-fragments hoisted above barrier
  short8 bf0[4], bf1[4];
  #pragma unroll
  for (int kk = 0; kk < 4; ++kk) {
    size_t base = (size_t)(0 * 4 + kk) * 512;
    bf0[kk] = *(const short8*)&wupk[base + h1 * 4 + g];
    bf1[kk] = *(const short8*)&wupk[base + h2 * 4 + g];
  }

  // ---- phase 1: feats -> LDS bf16, swizzled; rows 91..95 zero-padded
  #pragma unroll
  for (int i = 0; i < 6; ++i) {
    int c = t + i * 256;              // 1536 chunks of 8 bf16
    int r = c >> 4, d0 = (c & 15) * 8;
    uint4 pk4;
    if (r < NPG) {
      const float* src = fbase + r * D + d0;
      float4 f0 = *(const float4*)(src);
      float4 f1 = *(const float4*)(src + 4);
      pk4.x = bf16pk(f0.x, f0.y);
      pk4.y = bf16pk(f0.z, f0.w);
      pk4.z = bf16pk(f1.x, f1.y);
      pk4.w = bf16pk(f1.z, f1.w);
    } else {
      pk4.x = 0u; pk4.y = 0u; pk4.z = 0u; pk4.w = 0u;
    }
    int off = r * 256 + ((d0 * 2) ^ ((r & 7) << 4));
    *(uint4*)(lds + A_OFF + off) = pk4;
  }
  __syncthreads();

  for (int o = 0; o < 3; ++o) {
    if (o > 0) {
      #pragma unroll
      for (int kk = 0; kk < 4; ++kk) {
        size_t base = (size_t)(o * 4 + kk) * 512;
        bf0[kk] = *(const short8*)&wupk[base + h1 * 4 + g];
        bf1[kk] = *(const short8*)&wupk[base + h2 * 4 + g];
      }
    }
    const float bfva = bfva_a[o], bfvb = bfvb_a[o];
    const float wea = wea_a[o],  web = web_a[o];

    #pragma unroll 2
    for (int mt = 0; mt < 6; ++mt) {
      const int arow = mt * 16 + lm;
      const char* ab = lds + A_OFF + arow * 256;
      const int sa = (arow & 7) << 4;
      f32x4 acc0 = {0.f, 0.f, 0.f, 0.f};
      f32x4 acc1 = {0.f, 0.f, 0.f, 0.f};
      #pragma unroll
      for (int kk = 0; kk < 4; ++kk) {
        const int cb = kk * 64 + g * 16;   // same k-order as wupk layout
        short8 a = *(const short8*)(ab + (cb ^ sa));
        acc0 = __builtin_amdgcn_mfma_f32_16x16x32_bf16(a, bf0[kk], acc0, 0, 0, 0);
        acc1 = __builtin_amdgcn_mfma_f32_16x16x32_bf16(a, bf1[kk], acc1, 0, 0, 0);
      }
      #pragma unroll
      for (int r = 0; r < 4; ++r) {
        float v = sigf(acc0[r] + bfva) * wea + sigf(acc1[r] + bfvb) * web;
        v += __shfl_xor(v, 1);
        v += __shfl_xor(v, 2);
        v += __shfl_xor(v, 4);
        v += __shfl_xor(v, 8);
        if (lm == 0) ep[w][o][mt * 16 + g * 4 + r] = v;  // C/D: row=(l>>4)*4+r
      }
    }
  }
  __syncthreads();

  // ---- softmax per order (wave o handles order o, rows >= 91 masked)
  if (w < 3) {
    const int o = w;
    const int n1 = l, n2 = l + 64;
    float e1 = -1e30f, e2 = -1e30f;
    if (n1 < NPG) e1 = ep[0][o][n1] + ep[1][o][n1] + ep[2][o][n1] + ep[3][o][n1];
    if (n2 < NPG) e2 = ep[0][o][n2] + ep[1][o][n2] + ep[2][o][n2] + ep[3][o][n2];
    float mx = fmaxf(e1, e2);
    #pragma unroll
    for (int m = 1; m < 64; m <<= 1) mx = fmaxf(mx, __shfl_xor(mx, m));
    float x1 = (n1 < NPG) ? __expf(e1 - mx) : 0.f;
    float x2 = (n2 < NPG) ? __expf(e2 - mx) : 0.f;
    float s = x1 + x2;
    #pragma unroll
    for (int m = 1; m < 64; m <<= 1) s += __shfl_xor(s, m);
    float inv = __builtin_amdgcn_rcpf(s);
    if (n1 < NPG) alpha[o][n1] = x1 * inv;
    if (n2 < NPG) alpha[o][n2] = x2 * inv;
  }
  __syncthreads();

  // ---- weighted sum: float4 loads, 8-way node-parallel; part overlays A region
  {
    const int n_off = t >> 5;
    const int d4 = (t & 31) * 4;
    float a0x = 0.f, a0y = 0.f, a0z = 0.f, a0w = 0.f;
    float a1x = 0.f, a1y = 0.f, a1z = 0.f, a1w = 0.f;
    float a2x = 0.f, a2y = 0.f, a2z = 0.f, a2w = 0.f;
    for (int n = n_off; n < NPG; n += 8) {
      float4 f = *(const float4*)(fbase + n * D + d4);
      float al0 = alpha[0][n], al1 = alpha[1][n], al2 = alpha[2][n];
      a0x += f.x * al0; a0y += f.y * al0; a0z += f.z * al0; a0w += f.w * al0;
      a1x += f.x * al1; a1y += f.y * al1; a1z += f.z * al1; a1w += f.w * al1;
      a2x += f.x * al2; a2y += f.y * al2; a2z += f.z * al2; a2w += f.w * al2;
    }
    float* part = (float*)(lds + A_OFF);   // [8][384], overlays dead A tile
    float4 s0 = {a0x, a0y, a0z, a0w};
    float4 s1 = {a1x, a1y, a1z, a1w};
    float4 s2 = {a2x, a2y, a2z, a2w};
    *(float4*)&part[n_off * 384 + 0 * 128 + d4] = s0;
    *(float4*)&part[n_off * 384 + 1 * 128 + d4] = s1;
    *(float4*)&part[n_off * 384 + 2 * 128 + d4] = s2;
  }
  __syncthreads();
  {
    const float* part = (const float*)(lds + A_OFF);
    for (int slot = t; slot < 384; slot += 256) {
      float s = 0.f;
      #pragma unroll
      for (int j = 0; j < 8; ++j) s += part[j * 384 + slot];
      out[(size_t)b * 384 + slot] = s;
    }
  }
}

extern "C" void kernel_launch(void* const* d_in, const int* in_sizes, int n_in,
                              void* d_out, int out_size, void* d_ws, size_t ws_size,
                              hipStream_t stream) {
  const float* feats    = (const float*)d_in[0];
  const float* Wu       = (const float*)d_in[1];
  const float* bu       = (const float*)d_in[2];
  const float* Wv       = (const float*)d_in[3];
  const float* We       = (const float*)d_in[4];
  const int*   last_idx = (const int*)d_in[6];
  float* out = (float*)d_out;
  float* fvb  = (float*)d_ws;                              // 3*2048*128 f32 = 3 MB
  uint4* wupk = (uint4*)((char*)d_ws + 3 * NB * D * 4);    // 96 KB

  dim3 g0(128, 3);
  fv_kernel<<<g0, 256, 0, stream>>>(feats, Wv, bu, last_idx, fvb);
  wut_pack<<<12, 256, 0, stream>>>(Wu, wupk);
  sihg_main<<<NB, 256, 0, stream>>>(feats, wupk, We, fvb, out);
}